// Round 11
// baseline (236.941 us; speedup 1.0000x reference)
//
#include <hip/hip_runtime.h>
#include <math.h>

// RX gate on qubit 5 of 12, batch 4096 states of dim 4096.
// out_re[i] = c*sr[i] + s*si[i^64];  out_im[i] = c*si[i] - s*sr[i^64]
// (M = c*I - i*s*X_hyd is symmetric; X_hyd is the bit-6 flip permutation.)
//
// v11: the untested cache-flag quadrant {L1/L2 bypass, L3 ALLOCATE}.
//   plain loads            (L2 alloc, L3 alloc): ~80us  (L2 churn)
//   builtin NT loads       (L2 nt,    L3 nt)   : ~66us  (current best)
//   asm sc0 sc1 nt loads   (bypass,   L3 nt)   : ~67us  (v7)
//   asm sc0 sc1 loads      (bypass,   L3 alloc): THIS
// Mechanism: steady-state FETCH_SIZE = 67MB = exactly HALF the inputs miss
// L3 every iteration. Hypothesis: the NT flag marks input lines
// non-temporal in the MALL -> eager eviction of data we re-read every
// iteration. sc0 sc1 (no nt) keeps the L2-churn win (bypass) while letting
// the 256MiB MALL retain the inputs across iterations. Stores stay NT
// (no-allocate: outputs must not compete with inputs for L3; store policy
// proven neutral in v5-vs-v8).
// Control for this A/B: v7 (identical + nt) = 67us.

#define NQ_N 4096
#define NQ_BATCH 4096

typedef float f32x4 __attribute__((ext_vector_type(4)));

// total f32x4 vecs = 4096*4096/4 = 2^22 ; pairs = 2^21 ; 2 pairs/thread
#define TOTAL_PAIRS (1u << 21)
#define PAIR_OFFSET (1u << 20)   // second pair = first + half the pair space

__device__ __forceinline__ f32x4 ld_l3alloc(const f32x4* __restrict__ base,
                                            unsigned byte_off)
{
    f32x4 dst;
    asm volatile("global_load_dwordx4 %0, %1, %2 sc0 sc1"
                 : "=&v"(dst)
                 : "v"(byte_off), "s"(base)
                 : "memory");
    return dst;
}

__global__ __launch_bounds__(256)
void rx_l3keep_kernel(const f32x4* __restrict__ sr,
                      const f32x4* __restrict__ si,
                      const float* __restrict__ theta_p,
                      f32x4* __restrict__ out_re,
                      f32x4* __restrict__ out_im)
{
    const float half = 0.5f * theta_p[0];
    const float c = cosf(half);
    const float s = sinf(half);

    const unsigned u = blockIdx.x * blockDim.x + threadIdx.x; // pair id

    const unsigned p0 = u;
    const unsigned p1 = u + PAIR_OFFSET;

    // pair p -> vec index i with bit4 forced to 0: i = p + (p & ~15)
    const unsigned i0 = p0 + (p0 & ~15u);
    const unsigned j0 = i0 + 16;
    const unsigned i1 = p1 + (p1 & ~15u);
    const unsigned j1 = i1 + 16;

    // byte offsets (max vec index 2^22 -> max offset 2^26, fits 32-bit)
    const unsigned bi0 = i0 * 16u, bj0 = j0 * 16u;
    const unsigned bi1 = i1 * 16u, bj1 = j1 * 16u;

    // 8 independent bypass+L3-allocate loads, issued back-to-back
    const f32x4 rA = ld_l3alloc(sr, bi0);
    const f32x4 rB = ld_l3alloc(sr, bj0);
    const f32x4 mA = ld_l3alloc(si, bi0);
    const f32x4 mB = ld_l3alloc(si, bj0);
    const f32x4 rC = ld_l3alloc(sr, bi1);
    const f32x4 rD = ld_l3alloc(sr, bj1);
    const f32x4 mC = ld_l3alloc(si, bi1);
    const f32x4 mD = ld_l3alloc(si, bj1);

    // drain all loads; fence the scheduler so compute can't hoist (rule #18)
    asm volatile("s_waitcnt vmcnt(0)" ::: "memory");
    __builtin_amdgcn_sched_barrier(0);

    f32x4 reA, imA, reB, imB, reC, imC, reD, imD;
#pragma unroll
    for (int k = 0; k < 4; ++k) {
        reA[k] = fmaf(c, rA[k],  s * mB[k]);
        imA[k] = fmaf(c, mA[k], -s * rB[k]);
        reB[k] = fmaf(c, rB[k],  s * mA[k]);
        imB[k] = fmaf(c, mB[k], -s * rA[k]);
        reC[k] = fmaf(c, rC[k],  s * mD[k]);
        imC[k] = fmaf(c, mC[k], -s * rD[k]);
        reD[k] = fmaf(c, rD[k],  s * mC[k]);
        imD[k] = fmaf(c, mD[k], -s * rC[k]);
    }

    __builtin_nontemporal_store(reA, out_re + i0);
    __builtin_nontemporal_store(imA, out_im + i0);
    __builtin_nontemporal_store(reB, out_re + j0);
    __builtin_nontemporal_store(imB, out_im + j0);
    __builtin_nontemporal_store(reC, out_re + i1);
    __builtin_nontemporal_store(imC, out_im + i1);
    __builtin_nontemporal_store(reD, out_re + j1);
    __builtin_nontemporal_store(imD, out_im + j1);
}

extern "C" void kernel_launch(void* const* d_in, const int* in_sizes, int n_in,
                              void* d_out, int out_size, void* d_ws, size_t ws_size,
                              hipStream_t stream)
{
    const f32x4* sr = (const f32x4*)d_in[0];
    const f32x4* si = (const f32x4*)d_in[1];
    const float* th = (const float*)d_in[2];

    f32x4* out_re = (f32x4*)d_out;
    f32x4* out_im = out_re + ((size_t)NQ_BATCH * NQ_N / 4);

    const unsigned threads = TOTAL_PAIRS / 2;  // 2 pairs per thread -> 2^20
    const unsigned block = 256;
    const unsigned grid = threads / block;     // 4096

    rx_l3keep_kernel<<<grid, block, 0, stream>>>(sr, si, th, out_re, out_im);
}